// Round 5
// baseline (1905.566 us; speedup 1.0000x reference)
//
#include <hip/hip_runtime.h>
#include <hip/hip_bf16.h>
#include <hip/hip_fp16.h>

#define N_NODES 200000
#define N_EDGES 2500000
#define HID 32
#define BN_EPS 1e-5f

#define BKT_SHIFT 10                     // 1024 nodes per bucket
#define B_BKT ((N_NODES + 1023) / 1024)  // 196 buckets
#define PAD 16                           // one counter per 64B line
#define CAPB 14336                       // bucket capacity (mean 12800 + 13.6 sigma)
#define EDGES_PER_BLK 8192
#define NB_SCAT ((N_EDGES + EDGES_PER_BLK - 1) / EDGES_PER_BLK)  // 306

__device__ __forceinline__ void atomAddF(float* p, float v) {
    unsafeAtomicAdd(p, v);   // native global_atomic_add_f32 on gfx950
}

// K0: zero bucket cursors + stats scratch.
__global__ void k_init(int* __restrict__ bcur16, float* __restrict__ stats) {
    int i = blockIdx.x * blockDim.x + threadIdx.x;
    if (i < B_BKT * PAD) bcur16[i] = 0;
    if (i < 256) stats[i] = 0.0f;
}

// S1: scatter edges into capacity-padded buckets (grouped by dst>>10).
// 1024 threads x 8 edges: long per-bucket runs (42 edges ~ 334B ~ 5.2 lines)
// AND 16 waves/block for latency hiding. Edge data cached in registers
// between histogram and scatter phases (single read of ei).
__global__ void __launch_bounds__(1024)
k_scatter(const int* __restrict__ ei, int* __restrict__ bcur16,
          int2* __restrict__ ebuf) {
    __shared__ int lh[B_BKT], lbase[B_BKT], lc[B_BKT];
    int t = threadIdx.x;
    if (t < B_BKT) { lh[t] = 0; lc[t] = 0; }
    __syncthreads();
    int base = blockIdx.x * EDGES_PER_BLK;
    int sv[8], dv[8];
#pragma unroll
    for (int k = 0; k < 8; k++) {
        int e = base + k * 1024 + t;
        if (e < N_EDGES) {
            sv[k] = ei[e];
            dv[k] = ei[N_EDGES + e];
            atomicAdd(&lh[dv[k] >> BKT_SHIFT], 1);
        } else dv[k] = -1;
    }
    __syncthreads();
    if (t < B_BKT) lbase[t] = lh[t] ? atomicAdd(&bcur16[t * PAD], lh[t]) : 0;
    __syncthreads();
#pragma unroll
    for (int k = 0; k < 8; k++) {
        if (dv[k] >= 0) {
            int b = dv[k] >> BKT_SHIFT;
            int loc = atomicAdd(&lc[b], 1);
            ebuf[(size_t)b * CAPB + lbase[b] + loc] =
                make_int2(sv[k], dv[k] & 1023);
        }
    }
}

// S2: one block (1024 thr) per bucket. Fuses: per-node degree histogram,
// local exclusive scan (-> capacity-padded CSR row bases), norm=rsqrt(deg+1),
// xp=x*norm, and CSR placement (single-writer region -> dense lines).
__global__ void __launch_bounds__(1024)
k_bucket(const int2* __restrict__ ebuf, const int* __restrict__ bcur16,
         const float* __restrict__ x, int* __restrict__ rowbeg,
         int* __restrict__ cntg, float* __restrict__ norm,
         float* __restrict__ xp, int* __restrict__ csrc) {
    __shared__ int hist[1024], sh[1024], rbase[1024];
    int b = blockIdx.x;
    int t = threadIdx.x;
    int count = bcur16[b * PAD];
    size_t ebase = (size_t)b * CAPB;
    int nbase = b << BKT_SHIFT;
    hist[t] = 0;
    __syncthreads();
    for (int i = t; i < count; i += 1024) atomicAdd(&hist[ebuf[ebase + i].y], 1);
    __syncthreads();
    int v = hist[t];
    sh[t] = v;
    __syncthreads();
    for (int off = 1; off < 1024; off <<= 1) {
        int a = (t >= off) ? sh[t - off] : 0;
        __syncthreads();
        sh[t] += a;
        __syncthreads();
    }
    int rb = b * CAPB + (sh[t] - v);
    rbase[t] = rb;
    int n = nbase + t;
    if (n < N_NODES) {
        rowbeg[n] = rb;
        cntg[n] = v;
        float nm = rsqrtf((float)v + 1.0f);
        norm[n] = nm;
        xp[n] = x[n] * nm;
    }
    __syncthreads();
    hist[t] = 0;   // reuse as placement cursors
    __syncthreads();
    for (int i = t; i < count; i += 1024) {
        int2 e = ebuf[ebase + i];
        int loc = atomicAdd(&hist[e.y], 1);
        csrc[rbase[e.y] + loc] = e.x;
    }
}

// K5: layer-1 scalar gather s[n] = norm[n]*(xp[n] + sum xp[src]), with fused
// block-level sum/sumsq reduction into stats[0..1].
__global__ void __launch_bounds__(256)
k_gather1(const int* __restrict__ rowbeg, const int* __restrict__ cntg,
          const int* __restrict__ csrc, const float* __restrict__ xp,
          const float* __restrict__ norm, float* __restrict__ s,
          float* __restrict__ stats) {
    __shared__ float ls[256], lq[256];
    int n = blockIdx.x * blockDim.x + threadIdx.x;
    float val = 0.f;
    if (n < N_NODES) {
        int beg = rowbeg[n], dg = cntg[n];
        float acc = xp[n];
        for (int i = 0; i < dg; i++) acc += xp[csrc[beg + i]];
        val = norm[n] * acc;
        s[n] = val;
    }
    ls[threadIdx.x] = val; lq[threadIdx.x] = val * val;
    __syncthreads();
    for (int off = 128; off; off >>= 1) {
        if (threadIdx.x < (unsigned)off) {
            ls[threadIdx.x] += ls[threadIdx.x + off];
            lq[threadIdx.x] += lq[threadIdx.x + off];
        }
        __syncthreads();
    }
    if (threadIdx.x == 0) { atomAddF(&stats[0], ls[0]); atomAddF(&stats[1], lq[0]); }
}

// K7: fused layer-1 BN+ReLU (rank-1 form) + y1@W2, pre-scaled by norm[n].
// Writes A32 in fp32 (layer-2 messages stay full precision for accuracy).
__global__ void __launch_bounds__(256)
k_fusedA(const float* __restrict__ s, const float* __restrict__ norm,
         const float* __restrict__ stats, const float* __restrict__ W1,
         const float* __restrict__ g1, const float* __restrict__ be1,
         const float* __restrict__ W2, float* __restrict__ A32) {
    __shared__ float w2[32 * 32];
    __shared__ float aj[32], sj[32];
    __shared__ float y[8][33];
    int tid = threadIdx.x;
    for (int i = tid; i < 1024; i += 256) w2[i] = W2[i];
    if (tid < 32) {
        float m   = stats[0] * (1.0f / N_NODES);
        float var = stats[1] * (1.0f / N_NODES) - m * m;
        float w = W1[tid];
        float a = g1[tid] * w * rsqrtf(var * w * w + BN_EPS);
        aj[tid] = a;
        sj[tid] = be1[tid] - m * a;
    }
    int nl = tid >> 5, j = tid & 31;
    int n = blockIdx.x * 8 + nl;
    __syncthreads();
    float sv = (n < N_NODES) ? s[n] : 0.f;
    y[nl][j] = fmaxf(aj[j] * sv + sj[j], 0.f);
    __syncthreads();
    if (n < N_NODES) {
        float acc = 0.f;
#pragma unroll
        for (int k = 0; k < 32; k++) acc += y[nl][k] * w2[k * 32 + j];
        A32[n * 32 + j] = acc * norm[n];
    }
}

// K8a: CSR gather-aggregate, fp32 messages. 8 threads/node, float4 each.
// B[n] = norm[n]*(A32[n] + sum A32[src]); fused per-channel stats.
// Grid is exact: 200000 = 6250 * 32.
__global__ void __launch_bounds__(256)
k_gatherF(const int* __restrict__ rowbeg, const int* __restrict__ cntg,
          const int* __restrict__ csrc, const float* __restrict__ A,
          const float* __restrict__ norm, float* __restrict__ B,
          float* __restrict__ sum, float* __restrict__ sumsq) {
    __shared__ float ls[1024], lq[1024];
    int tid = threadIdx.x;
    int nl = tid >> 3;            // 0..31
    int cg = tid & 7;             // channel group
    int c = cg * 4;
    int n = blockIdx.x * 32 + nl;
    int beg = rowbeg[n], dg = cntg[n];
    float4 acc = *(const float4*)(A + n * 32 + c);    // self-loop term
    int i = 0;
    for (; i + 1 < dg; i += 2) {
        int s0 = csrc[beg + i], s1 = csrc[beg + i + 1];
        float4 v0 = *(const float4*)(A + s0 * 32 + c);
        float4 v1 = *(const float4*)(A + s1 * 32 + c);
        acc.x += v0.x + v1.x; acc.y += v0.y + v1.y;
        acc.z += v0.z + v1.z; acc.w += v0.w + v1.w;
    }
    if (i < dg) {
        float4 v = *(const float4*)(A + csrc[beg + i] * 32 + c);
        acc.x += v.x; acc.y += v.y; acc.z += v.z; acc.w += v.w;
    }
    float nm = norm[n];
    float4 o = make_float4(acc.x * nm, acc.y * nm, acc.z * nm, acc.w * nm);
    *(float4*)(B + n * 32 + c) = o;
    // fused stats: reduce over the 32 nodes of this block per channel
    int idx = tid * 4;
    ls[idx] = o.x; ls[idx + 1] = o.y; ls[idx + 2] = o.z; ls[idx + 3] = o.w;
    lq[idx] = o.x * o.x; lq[idx + 1] = o.y * o.y;
    lq[idx + 2] = o.z * o.z; lq[idx + 3] = o.w * o.w;
    __syncthreads();
    for (int off = 16; off; off >>= 1) {
        if (nl < off) {
#pragma unroll
            for (int k = 0; k < 4; k++) {
                ls[idx + k] += ls[idx + off * 32 + k];
                lq[idx + k] += lq[idx + off * 32 + k];
            }
        }
        __syncthreads();
    }
    if (nl == 0) {
#pragma unroll
        for (int k = 0; k < 4; k++) {
            atomAddF(&sum[c + k], ls[idx + k]);
            atomAddF(&sumsq[c + k], lq[idx + k]);
        }
    }
}

// K10: fused BN+ReLU + y@W, pre-scaled by norm[n]. Reads B fp32, writes A16.
__global__ void __launch_bounds__(256)
k_fusedB(const float* __restrict__ norm, const float* __restrict__ sum,
         const float* __restrict__ sumsq, const float* __restrict__ g,
         const float* __restrict__ be, const float* __restrict__ W,
         const float* __restrict__ aggIn, __half* __restrict__ hOut) {
    __shared__ float wl[1024];
    __shared__ float sc[32], sh[32];
    __shared__ float y[8][33];
    int tid = threadIdx.x;
    for (int i = tid; i < 1024; i += 256) wl[i] = W[i];
    if (tid < 32) {
        float m   = sum[tid] * (1.0f / N_NODES);
        float var = sumsq[tid] * (1.0f / N_NODES) - m * m;
        float scj = g[tid] * rsqrtf(var + BN_EPS);
        sc[tid] = scj;
        sh[tid] = be[tid] - m * scj;
    }
    int nl = tid >> 5, j = tid & 31;
    int n = blockIdx.x * 8 + nl;
    __syncthreads();
    float yv = 0.f;
    if (n < N_NODES) yv = fmaxf(sc[j] * aggIn[n * 32 + j] + sh[j], 0.f);
    y[nl][j] = yv;
    __syncthreads();
    if (n < N_NODES) {
        float acc = 0.f;
#pragma unroll
        for (int k = 0; k < 32; k++) acc += y[nl][k] * wl[k * 32 + j];
        hOut[n * 32 + j] = __float2half(acc * norm[n]);
    }
}

__device__ __forceinline__ void load8h(const __half* p, float2& f0, float2& f1,
                                       float2& f2, float2& f3) {
    float4 raw = *(const float4*)p;              // one 16B load
    const __half2* h = (const __half2*)&raw;
    f0 = __half22float2(h[0]);
    f1 = __half22float2(h[1]);
    f2 = __half22float2(h[2]);
    f3 = __half22float2(h[3]);
}

// K8b: CSR gather-aggregate, f16 messages. 4 threads/node, 8 channels each.
// Fused per-channel stats. Grid exact: 200000 = 3125 * 64.
__global__ void __launch_bounds__(256)
k_gatherH(const int* __restrict__ rowbeg, const int* __restrict__ cntg,
          const int* __restrict__ csrc, const __half* __restrict__ A,
          const float* __restrict__ norm, float* __restrict__ B,
          float* __restrict__ sum, float* __restrict__ sumsq) {
    __shared__ float ls[2048], lq[2048];
    int tid = threadIdx.x;
    int nl = tid >> 2;            // 0..63
    int cg = tid & 3;
    int c8 = cg * 8;
    int n = blockIdx.x * 64 + nl;
    int beg = rowbeg[n], dg = cntg[n];
    float2 a0, a1, a2, a3;
    load8h(A + n * 32 + c8, a0, a1, a2, a3);   // self-loop term
    int i = 0;
    for (; i + 1 < dg; i += 2) {
        int s0 = csrc[beg + i], s1 = csrc[beg + i + 1];
        float2 b0, b1, b2, b3, c0, c1, c2, c3;
        load8h(A + s0 * 32 + c8, b0, b1, b2, b3);
        load8h(A + s1 * 32 + c8, c0, c1, c2, c3);
        a0.x += b0.x + c0.x; a0.y += b0.y + c0.y;
        a1.x += b1.x + c1.x; a1.y += b1.y + c1.y;
        a2.x += b2.x + c2.x; a2.y += b2.y + c2.y;
        a3.x += b3.x + c3.x; a3.y += b3.y + c3.y;
    }
    if (i < dg) {
        float2 b0, b1, b2, b3;
        load8h(A + csrc[beg + i] * 32 + c8, b0, b1, b2, b3);
        a0.x += b0.x; a0.y += b0.y; a1.x += b1.x; a1.y += b1.y;
        a2.x += b2.x; a2.y += b2.y; a3.x += b3.x; a3.y += b3.y;
    }
    float nm = norm[n];
    float o[8] = {a0.x * nm, a0.y * nm, a1.x * nm, a1.y * nm,
                  a2.x * nm, a2.y * nm, a3.x * nm, a3.y * nm};
    *(float4*)(B + n * 32 + c8)     = make_float4(o[0], o[1], o[2], o[3]);
    *(float4*)(B + n * 32 + c8 + 4) = make_float4(o[4], o[5], o[6], o[7]);
    int idx = tid * 8;
#pragma unroll
    for (int k = 0; k < 8; k++) { ls[idx + k] = o[k]; lq[idx + k] = o[k] * o[k]; }
    __syncthreads();
    for (int off = 32; off; off >>= 1) {
        if (nl < off) {
#pragma unroll
            for (int k = 0; k < 8; k++) {
                ls[idx + k] += ls[idx + off * 32 + k];
                lq[idx + k] += lq[idx + off * 32 + k];
            }
        }
        __syncthreads();
    }
    if (nl == 0) {
#pragma unroll
        for (int k = 0; k < 8; k++) {
            atomAddF(&sum[c8 + k], ls[idx + k]);
            atomAddF(&sumsq[c8 + k], lq[idx + k]);
        }
    }
}

// K11: final BN+ReLU + dot with fcW + fcb.
__global__ void __launch_bounds__(256)
k_final(const float* __restrict__ aggIn, const float* __restrict__ sum,
        const float* __restrict__ sumsq, const float* __restrict__ g,
        const float* __restrict__ be, const float* __restrict__ fcW,
        const float* __restrict__ fcb, float* __restrict__ out) {
    __shared__ float sc[32], sh[32], fw[32];
    int tid = threadIdx.x;
    if (tid < 32) {
        float m   = sum[tid] * (1.0f / N_NODES);
        float var = sumsq[tid] * (1.0f / N_NODES) - m * m;
        float scj = g[tid] * rsqrtf(var + BN_EPS);
        sc[tid] = scj;
        sh[tid] = be[tid] - m * scj;
        fw[tid] = fcW[tid];
    }
    __syncthreads();
    int nl = tid >> 5, j = tid & 31;
    int n = blockIdx.x * 8 + nl;
    float v = 0.f;
    if (n < N_NODES) v = fmaxf(sc[j] * aggIn[n * 32 + j] + sh[j], 0.f) * fw[j];
    for (int off = 16; off; off >>= 1) v += __shfl_down(v, off, 32);
    if (j == 0 && n < N_NODES) out[n] = v + fcb[0];
}

extern "C" void kernel_launch(void* const* d_in, const int* in_sizes, int n_in,
                              void* d_out, int out_size, void* d_ws, size_t ws_size,
                              hipStream_t stream) {
    const float* x   = (const float*)d_in[0];
    const int*   ei  = (const int*)d_in[1];
    // d_in[2] edge_attr: unused by the reference
    const float* W1  = (const float*)d_in[3];
    // b1/b2/b3 cancel under training-mode BN
    const float* g1  = (const float*)d_in[5];
    const float* be1 = (const float*)d_in[6];
    const float* W2  = (const float*)d_in[7];
    const float* g2  = (const float*)d_in[9];
    const float* be2 = (const float*)d_in[10];
    const float* W3  = (const float*)d_in[11];
    const float* g3  = (const float*)d_in[13];
    const float* be3 = (const float*)d_in[14];
    const float* fcW = (const float*)d_in[15];
    const float* fcb = (const float*)d_in[16];
    float* out = (float*)d_out;

    // Workspace layout (bytes). Region0 [0, 25.6M) is time-multiplexed:
    //   ebuf int2[196*14336] = 22.5MB   (last read: k_bucket)
    //   A32  fp32 N*32       = 25.6MB   (written k_fusedA, last read k_gatherF)
    //   A16  f16  N*32       = 12.8MB   (written k_fusedB, read k_gatherH)
    // All uses are strictly ordered by dispatch, so overlay is safe.
    char* base = (char*)d_ws;
    float*  A32    = (float*)base;
    __half* A16    = (__half*)base;
    int2*   ebuf   = (int2*)base;
    float*  B      = (float*)(base + (size_t)N_NODES * 32 * 4);      // 25.6MB
    int*    csrc   = (int*)(base + (size_t)N_NODES * 32 * 8);       // 11.2MB
    int*    rowbeg = csrc + (size_t)B_BKT * CAPB;
    int*    cntg   = rowbeg + N_NODES;
    float*  norm   = (float*)(cntg + N_NODES);
    float*  xp     = norm + N_NODES;
    float*  s      = xp + N_NODES;
    float*  stats  = s + N_NODES;                  // [256]
    int*    bcur16 = (int*)(stats + 256);          // [B_BKT*16]

    const int nbN = (N_NODES + 255) / 256;
    const int nbZ = (B_BKT * PAD + 255) / 256;
    const int nbNode8 = (N_NODES + 7) / 8;

    k_init   <<<nbZ, 256, 0, stream>>>(bcur16, stats);
    k_scatter<<<NB_SCAT, 1024, 0, stream>>>(ei, bcur16, ebuf);
    k_bucket <<<B_BKT, 1024, 0, stream>>>(ebuf, bcur16, x, rowbeg, cntg, norm, xp, csrc);
    k_gather1<<<nbN, 256, 0, stream>>>(rowbeg, cntg, csrc, xp, norm, s, stats);
    k_fusedA <<<nbNode8, 256, 0, stream>>>(s, norm, stats, W1, g1, be1, W2, A32);
    k_gatherF<<<N_NODES / 32, 256, 0, stream>>>(rowbeg, cntg, csrc, A32, norm, B,
                                                stats + 8, stats + 40);
    k_fusedB <<<nbNode8, 256, 0, stream>>>(norm, stats + 8, stats + 40, g2, be2, W3, B, A16);
    k_gatherH<<<N_NODES / 64, 256, 0, stream>>>(rowbeg, cntg, csrc, A16, norm, B,
                                                stats + 72, stats + 104);
    k_final  <<<nbNode8, 256, 0, stream>>>(B, stats + 72, stats + 104, g3, be3, fcW, fcb, out);
}

// Round 6
// 411.987 us; speedup vs baseline: 4.6253x; 4.6253x over previous
//
#include <hip/hip_runtime.h>
#include <hip/hip_bf16.h>
#include <hip/hip_fp16.h>

#define N_NODES 200000
#define N_EDGES 2500000
#define HID 32
#define BN_EPS 1e-5f

#define BKT_SHIFT 10                     // 1024 nodes per bucket
#define B_BKT ((N_NODES + 1023) / 1024)  // 196 buckets
#define PAD 16                           // one counter per 64B line
#define CAPB 14336                       // bucket capacity (mean 12800 + 13.6 sigma)
#define EDGES_PER_BLK 8192
#define NB_SCAT ((N_EDGES + EDGES_PER_BLK - 1) / EDGES_PER_BLK)  // 306

// Padded BN-stats layout: accumulator for channel j lives at p[j*16]
// (64 B apart -> own cache line -> atomics parallel across TCC banks).
#define SSTR 16

__device__ __forceinline__ void atomAddF(float* p, float v) {
    unsafeAtomicAdd(p, v);   // native global_atomic_add_f32 on gfx950
}

// K0: zero bucket cursors + (padded) stats scratch.
__global__ void k_init(int* __restrict__ bcur16, float* __restrict__ stats) {
    int i = blockIdx.x * blockDim.x + threadIdx.x;
    if (i < B_BKT * PAD) bcur16[i] = 0;
    if (i < 4096) stats[i] = 0.0f;
}

// S1: scatter edges into capacity-padded buckets (grouped by dst>>10).
// 1024 threads x 8 edges: long per-bucket runs (~42 edges ~ 334B) AND 16
// waves/block. Edge data cached in registers between phases (single ei read).
__global__ void __launch_bounds__(1024)
k_scatter(const int* __restrict__ ei, int* __restrict__ bcur16,
          int2* __restrict__ ebuf) {
    __shared__ int lh[B_BKT], lbase[B_BKT], lc[B_BKT];
    int t = threadIdx.x;
    if (t < B_BKT) { lh[t] = 0; lc[t] = 0; }
    __syncthreads();
    int base = blockIdx.x * EDGES_PER_BLK;
    int sv[8], dv[8];
#pragma unroll
    for (int k = 0; k < 8; k++) {
        int e = base + k * 1024 + t;
        if (e < N_EDGES) {
            sv[k] = ei[e];
            dv[k] = ei[N_EDGES + e];
            atomicAdd(&lh[dv[k] >> BKT_SHIFT], 1);
        } else dv[k] = -1;
    }
    __syncthreads();
    if (t < B_BKT) lbase[t] = lh[t] ? atomicAdd(&bcur16[t * PAD], lh[t]) : 0;
    __syncthreads();
#pragma unroll
    for (int k = 0; k < 8; k++) {
        if (dv[k] >= 0) {
            int b = dv[k] >> BKT_SHIFT;
            int loc = atomicAdd(&lc[b], 1);
            ebuf[(size_t)b * CAPB + lbase[b] + loc] =
                make_int2(sv[k], dv[k] & 1023);
        }
    }
}

// S2: one block (1024 thr) per bucket. Fuses: per-node degree histogram,
// local exclusive scan (-> capacity-padded CSR row bases), norm=rsqrt(deg+1),
// xp=x*norm, and CSR placement (single-writer region -> dense lines).
__global__ void __launch_bounds__(1024)
k_bucket(const int2* __restrict__ ebuf, const int* __restrict__ bcur16,
         const float* __restrict__ x, int* __restrict__ rowbeg,
         int* __restrict__ cntg, float* __restrict__ norm,
         float* __restrict__ xp, int* __restrict__ csrc) {
    __shared__ int hist[1024], sh[1024], rbase[1024];
    int b = blockIdx.x;
    int t = threadIdx.x;
    int count = bcur16[b * PAD];
    size_t ebase = (size_t)b * CAPB;
    int nbase = b << BKT_SHIFT;
    hist[t] = 0;
    __syncthreads();
    for (int i = t; i < count; i += 1024) atomicAdd(&hist[ebuf[ebase + i].y], 1);
    __syncthreads();
    int v = hist[t];
    sh[t] = v;
    __syncthreads();
    for (int off = 1; off < 1024; off <<= 1) {
        int a = (t >= off) ? sh[t - off] : 0;
        __syncthreads();
        sh[t] += a;
        __syncthreads();
    }
    int rb = b * CAPB + (sh[t] - v);
    rbase[t] = rb;
    int n = nbase + t;
    if (n < N_NODES) {
        rowbeg[n] = rb;
        cntg[n] = v;
        float nm = rsqrtf((float)v + 1.0f);
        norm[n] = nm;
        xp[n] = x[n] * nm;
    }
    __syncthreads();
    hist[t] = 0;   // reuse as placement cursors
    __syncthreads();
    for (int i = t; i < count; i += 1024) {
        int2 e = ebuf[ebase + i];
        int loc = atomicAdd(&hist[e.y], 1);
        csrc[rbase[e.y] + loc] = e.x;
    }
}

// K5: layer-1 scalar gather s[n] = norm[n]*(xp[n] + sum xp[src]), with fused
// block-level sum/sumsq (only 2 atomics per block -> 782 total: benign).
__global__ void __launch_bounds__(256)
k_gather1(const int* __restrict__ rowbeg, const int* __restrict__ cntg,
          const int* __restrict__ csrc, const float* __restrict__ xp,
          const float* __restrict__ norm, float* __restrict__ s,
          float* __restrict__ stats) {
    __shared__ float ls[256], lq[256];
    int n = blockIdx.x * blockDim.x + threadIdx.x;
    float val = 0.f;
    if (n < N_NODES) {
        int beg = rowbeg[n], dg = cntg[n];
        float acc = xp[n];
        for (int i = 0; i < dg; i++) acc += xp[csrc[beg + i]];
        val = norm[n] * acc;
        s[n] = val;
    }
    ls[threadIdx.x] = val; lq[threadIdx.x] = val * val;
    __syncthreads();
    for (int off = 128; off; off >>= 1) {
        if (threadIdx.x < (unsigned)off) {
            ls[threadIdx.x] += ls[threadIdx.x + off];
            lq[threadIdx.x] += lq[threadIdx.x + off];
        }
        __syncthreads();
    }
    if (threadIdx.x == 0) { atomAddF(&stats[0], ls[0]); atomAddF(&stats[1], lq[0]); }
}

// K7: fused layer-1 BN+ReLU (rank-1 form) + y1@W2, pre-scaled by norm[n].
// Writes A32 in fp32 (layer-2 messages stay full precision for accuracy).
__global__ void __launch_bounds__(256)
k_fusedA(const float* __restrict__ s, const float* __restrict__ norm,
         const float* __restrict__ stats, const float* __restrict__ W1,
         const float* __restrict__ g1, const float* __restrict__ be1,
         const float* __restrict__ W2, float* __restrict__ A32) {
    __shared__ float w2[32 * 32];
    __shared__ float aj[32], sj[32];
    __shared__ float y[8][33];
    int tid = threadIdx.x;
    for (int i = tid; i < 1024; i += 256) w2[i] = W2[i];
    if (tid < 32) {
        float m   = stats[0] * (1.0f / N_NODES);
        float var = stats[1] * (1.0f / N_NODES) - m * m;
        float w = W1[tid];
        float a = g1[tid] * w * rsqrtf(var * w * w + BN_EPS);
        aj[tid] = a;
        sj[tid] = be1[tid] - m * a;
    }
    int nl = tid >> 5, j = tid & 31;
    int n = blockIdx.x * 8 + nl;
    __syncthreads();
    float sv = (n < N_NODES) ? s[n] : 0.f;
    y[nl][j] = fmaxf(aj[j] * sv + sj[j], 0.f);
    __syncthreads();
    if (n < N_NODES) {
        float acc = 0.f;
#pragma unroll
        for (int k = 0; k < 32; k++) acc += y[nl][k] * w2[k * 32 + j];
        A32[n * 32 + j] = acc * norm[n];
    }
}

// K8a: CSR gather-aggregate, fp32 messages. 8 threads/node, float4 each.
// B[n] = norm[n]*(A32[n] + sum A32[src]).  NO epilogue (stats separate).
__global__ void __launch_bounds__(256)
k_gatherF(const int* __restrict__ rowbeg, const int* __restrict__ cntg,
          const int* __restrict__ csrc, const float* __restrict__ A,
          const float* __restrict__ norm, float* __restrict__ B) {
    int tid = threadIdx.x;
    int n = blockIdx.x * 32 + (tid >> 3);
    if (n >= N_NODES) return;
    int c = (tid & 7) * 4;
    int beg = rowbeg[n], dg = cntg[n];
    float4 acc = *(const float4*)(A + n * 32 + c);    // self-loop term
    int i = 0;
    for (; i + 1 < dg; i += 2) {
        int s0 = csrc[beg + i], s1 = csrc[beg + i + 1];
        float4 v0 = *(const float4*)(A + s0 * 32 + c);
        float4 v1 = *(const float4*)(A + s1 * 32 + c);
        acc.x += v0.x + v1.x; acc.y += v0.y + v1.y;
        acc.z += v0.z + v1.z; acc.w += v0.w + v1.w;
    }
    if (i < dg) {
        float4 v = *(const float4*)(A + csrc[beg + i] * 32 + c);
        acc.x += v.x; acc.y += v.y; acc.z += v.z; acc.w += v.w;
    }
    float nm = norm[n];
    float4 o = make_float4(acc.x * nm, acc.y * nm, acc.z * nm, acc.w * nm);
    *(float4*)(B + n * 32 + c) = o;
}

// K9: per-channel sum/sumsq, PADDED accumulators (sum[j*SSTR], 64B apart ->
// atomics spread across TCC banks; 512 atomics per address).
__global__ void k_stats32(const float* __restrict__ agg, float* __restrict__ sum,
                          float* __restrict__ sumsq) {
    int j = threadIdx.x & 31;
    int rl = threadIdx.x >> 5;   // 0..7
    float a = 0.f, q = 0.f;
    for (int n = blockIdx.x * 8 + rl; n < N_NODES; n += gridDim.x * 8) {
        float v = agg[n * 32 + j];
        a += v; q += v * v;
    }
    __shared__ float ls[8][32], lq[8][32];
    ls[rl][j] = a; lq[rl][j] = q;
    __syncthreads();
    for (int off = 4; off; off >>= 1) {
        if (rl < off) { ls[rl][j] += ls[rl + off][j]; lq[rl][j] += lq[rl + off][j]; }
        __syncthreads();
    }
    if (rl == 0) { atomAddF(&sum[j * SSTR], ls[0][j]); atomAddF(&sumsq[j * SSTR], lq[0][j]); }
}

// K10: fused BN+ReLU + y@W, pre-scaled by norm[n]. Reads B fp32, writes A16.
// Reads padded stats.
__global__ void __launch_bounds__(256)
k_fusedB(const float* __restrict__ norm, const float* __restrict__ sum,
         const float* __restrict__ sumsq, const float* __restrict__ g,
         const float* __restrict__ be, const float* __restrict__ W,
         const float* __restrict__ aggIn, __half* __restrict__ hOut) {
    __shared__ float wl[1024];
    __shared__ float sc[32], sh[32];
    __shared__ float y[8][33];
    int tid = threadIdx.x;
    for (int i = tid; i < 1024; i += 256) wl[i] = W[i];
    if (tid < 32) {
        float m   = sum[tid * SSTR] * (1.0f / N_NODES);
        float var = sumsq[tid * SSTR] * (1.0f / N_NODES) - m * m;
        float scj = g[tid] * rsqrtf(var + BN_EPS);
        sc[tid] = scj;
        sh[tid] = be[tid] - m * scj;
    }
    int nl = tid >> 5, j = tid & 31;
    int n = blockIdx.x * 8 + nl;
    __syncthreads();
    float yv = 0.f;
    if (n < N_NODES) yv = fmaxf(sc[j] * aggIn[n * 32 + j] + sh[j], 0.f);
    y[nl][j] = yv;
    __syncthreads();
    if (n < N_NODES) {
        float acc = 0.f;
#pragma unroll
        for (int k = 0; k < 32; k++) acc += y[nl][k] * wl[k * 32 + j];
        hOut[n * 32 + j] = __float2half(acc * norm[n]);
    }
}

__device__ __forceinline__ void load8h(const __half* p, float2& f0, float2& f1,
                                       float2& f2, float2& f3) {
    float4 raw = *(const float4*)p;              // one 16B load
    const __half2* h = (const __half2*)&raw;
    f0 = __half22float2(h[0]);
    f1 = __half22float2(h[1]);
    f2 = __half22float2(h[2]);
    f3 = __half22float2(h[3]);
}

// K8b: CSR gather-aggregate, f16 messages. 4 threads/node, 8 channels each.
// NO epilogue.
__global__ void __launch_bounds__(256)
k_gatherH(const int* __restrict__ rowbeg, const int* __restrict__ cntg,
          const int* __restrict__ csrc, const __half* __restrict__ A,
          const float* __restrict__ norm, float* __restrict__ B) {
    int tid = threadIdx.x;
    int n = blockIdx.x * 64 + (tid >> 2);
    if (n >= N_NODES) return;
    int c8 = (tid & 3) * 8;
    int beg = rowbeg[n], dg = cntg[n];
    float2 a0, a1, a2, a3;
    load8h(A + n * 32 + c8, a0, a1, a2, a3);   // self-loop term
    int i = 0;
    for (; i + 1 < dg; i += 2) {
        int s0 = csrc[beg + i], s1 = csrc[beg + i + 1];
        float2 b0, b1, b2, b3, c0, c1, c2, c3;
        load8h(A + s0 * 32 + c8, b0, b1, b2, b3);
        load8h(A + s1 * 32 + c8, c0, c1, c2, c3);
        a0.x += b0.x + c0.x; a0.y += b0.y + c0.y;
        a1.x += b1.x + c1.x; a1.y += b1.y + c1.y;
        a2.x += b2.x + c2.x; a2.y += b2.y + c2.y;
        a3.x += b3.x + c3.x; a3.y += b3.y + c3.y;
    }
    if (i < dg) {
        float2 b0, b1, b2, b3;
        load8h(A + csrc[beg + i] * 32 + c8, b0, b1, b2, b3);
        a0.x += b0.x; a0.y += b0.y; a1.x += b1.x; a1.y += b1.y;
        a2.x += b2.x; a2.y += b2.y; a3.x += b3.x; a3.y += b3.y;
    }
    float nm = norm[n];
    float4 o0 = make_float4(a0.x * nm, a0.y * nm, a1.x * nm, a1.y * nm);
    float4 o1 = make_float4(a2.x * nm, a2.y * nm, a3.x * nm, a3.y * nm);
    *(float4*)(B + n * 32 + c8) = o0;
    *(float4*)(B + n * 32 + c8 + 4) = o1;
}

// K11: final BN+ReLU + dot with fcW + fcb. Reads padded stats.
__global__ void __launch_bounds__(256)
k_final(const float* __restrict__ aggIn, const float* __restrict__ sum,
        const float* __restrict__ sumsq, const float* __restrict__ g,
        const float* __restrict__ be, const float* __restrict__ fcW,
        const float* __restrict__ fcb, float* __restrict__ out) {
    __shared__ float sc[32], sh[32], fw[32];
    int tid = threadIdx.x;
    if (tid < 32) {
        float m   = sum[tid * SSTR] * (1.0f / N_NODES);
        float var = sumsq[tid * SSTR] * (1.0f / N_NODES) - m * m;
        float scj = g[tid] * rsqrtf(var + BN_EPS);
        sc[tid] = scj;
        sh[tid] = be[tid] - m * scj;
        fw[tid] = fcW[tid];
    }
    __syncthreads();
    int nl = tid >> 5, j = tid & 31;
    int n = blockIdx.x * 8 + nl;
    float v = 0.f;
    if (n < N_NODES) v = fmaxf(sc[j] * aggIn[n * 32 + j] + sh[j], 0.f) * fw[j];
    for (int off = 16; off; off >>= 1) v += __shfl_down(v, off, 32);
    if (j == 0 && n < N_NODES) out[n] = v + fcb[0];
}

extern "C" void kernel_launch(void* const* d_in, const int* in_sizes, int n_in,
                              void* d_out, int out_size, void* d_ws, size_t ws_size,
                              hipStream_t stream) {
    const float* x   = (const float*)d_in[0];
    const int*   ei  = (const int*)d_in[1];
    // d_in[2] edge_attr: unused by the reference
    const float* W1  = (const float*)d_in[3];
    // b1/b2/b3 cancel under training-mode BN
    const float* g1  = (const float*)d_in[5];
    const float* be1 = (const float*)d_in[6];
    const float* W2  = (const float*)d_in[7];
    const float* g2  = (const float*)d_in[9];
    const float* be2 = (const float*)d_in[10];
    const float* W3  = (const float*)d_in[11];
    const float* g3  = (const float*)d_in[13];
    const float* be3 = (const float*)d_in[14];
    const float* fcW = (const float*)d_in[15];
    const float* fcb = (const float*)d_in[16];
    float* out = (float*)d_out;

    // Workspace layout. Region0 [0, 25.6M) is time-multiplexed:
    //   ebuf int2[196*14336] = 22.5MB (last read k_bucket)
    //   A32 fp32 N*32 = 25.6MB (k_fusedA -> k_gatherF)
    //   A16 f16  N*32 = 12.8MB (k_fusedB -> k_gatherH)
    // All uses strictly ordered by dispatch.
    // Padded stats layout (floats, stride SSTR=16 per channel):
    //   [0..1]   layer-1 scalar sum/sumsq
    //   [8   .. 8+511]    L2 sum     (j*16)
    //   [520 .. 520+511]  L2 sumsq
    //   [1032.. 1032+511] L3 sum
    //   [1544.. 1544+511] L3 sumsq
    char* base = (char*)d_ws;
    float*  A32    = (float*)base;
    __half* A16    = (__half*)base;
    int2*   ebuf   = (int2*)base;
    float*  B      = (float*)(base + (size_t)N_NODES * 32 * 4);   // 25.6MB
    int*    csrc   = (int*)(base + (size_t)N_NODES * 32 * 8);     // 11.2MB
    int*    rowbeg = csrc + (size_t)B_BKT * CAPB;
    int*    cntg   = rowbeg + N_NODES;
    float*  norm   = (float*)(cntg + N_NODES);
    float*  xp     = norm + N_NODES;
    float*  s      = xp + N_NODES;
    float*  stats  = s + N_NODES;                  // [4096]
    int*    bcur16 = (int*)(stats + 4096);         // [B_BKT*16]

    const int nbN = (N_NODES + 255) / 256;
    const int nbZ = (4096 + 255) / 256;            // covers B_BKT*PAD=3136 too
    const int nbNode8 = (N_NODES + 7) / 8;

    k_init   <<<nbZ, 256, 0, stream>>>(bcur16, stats);
    k_scatter<<<NB_SCAT, 1024, 0, stream>>>(ei, bcur16, ebuf);
    k_bucket <<<B_BKT, 1024, 0, stream>>>(ebuf, bcur16, x, rowbeg, cntg, norm, xp, csrc);
    k_gather1<<<nbN, 256, 0, stream>>>(rowbeg, cntg, csrc, xp, norm, s, stats);
    k_fusedA <<<nbNode8, 256, 0, stream>>>(s, norm, stats, W1, g1, be1, W2, A32);
    k_gatherF<<<N_NODES / 32, 256, 0, stream>>>(rowbeg, cntg, csrc, A32, norm, B);
    k_stats32<<<512, 256, 0, stream>>>(B, stats + 8, stats + 520);
    k_fusedB <<<nbNode8, 256, 0, stream>>>(norm, stats + 8, stats + 520, g2, be2, W3, B, A16);
    k_gatherH<<<N_NODES / 64, 256, 0, stream>>>(rowbeg, cntg, csrc, A16, norm, B);
    k_stats32<<<512, 256, 0, stream>>>(B, stats + 1032, stats + 1544);
    k_final  <<<nbNode8, 256, 0, stream>>>(B, stats + 1032, stats + 1544, g3, be3, fcW, fcb, out);
}

// Round 7
// 393.741 us; speedup vs baseline: 4.8396x; 1.0463x over previous
//
#include <hip/hip_runtime.h>
#include <hip/hip_bf16.h>
#include <hip/hip_fp16.h>

#define N_NODES 200000
#define N_EDGES 2500000
#define HID 32
#define BN_EPS 1e-5f

#define BKT_SHIFT 10                     // 1024 nodes per bucket
#define B_BKT ((N_NODES + 1023) / 1024)  // 196 buckets
#define PAD 16                           // one counter per 64B line
#define CAPB 14336                       // bucket capacity (mean 12800 + 13.6 sigma)
#define EDGES_PER_BLK 8192
#define NB_SCAT ((N_EDGES + EDGES_PER_BLK - 1) / EDGES_PER_BLK)  // 306

// Padded BN-stats: accumulator for channel j at p[j*16] (64B apart -> own
// TCC line -> atomics parallel across channels).
#define SSTR 16
// stats float offsets
#define S1SUM 0
#define S1SQ  16
#define L2SUM 32
#define L2SQ  (L2SUM + 32 * SSTR)
#define L3SUM (L2SQ + 32 * SSTR)
#define L3SQ  (L3SUM + 32 * SSTR)

#define NBF 1250   // gatherF blocks (x5 iters x32 nodes = 200000)
#define ITF 5
#define NBH 625    // gatherH blocks (x5 iters x64 nodes = 200000)
#define ITH 5

__device__ __forceinline__ void atomAddF(float* p, float v) {
    unsafeAtomicAdd(p, v);   // native global_atomic_add_f32 on gfx950
}

// K0: zero bucket cursors + (padded) stats scratch.
__global__ void k_init(int* __restrict__ bcur16, float* __restrict__ stats) {
    int i = blockIdx.x * blockDim.x + threadIdx.x;
    if (i < B_BKT * PAD) bcur16[i] = 0;
    if (i < 4096) stats[i] = 0.0f;
}

// S1: scatter edges into capacity-padded buckets (dst>>10), PACKED:
// word = (local_dst<<18) | src   (src < 2^18). 1024 thr x 8 edges: long
// per-bucket runs AND 16 waves/block; edges register-cached between phases.
__global__ void __launch_bounds__(1024)
k_scatter(const int* __restrict__ ei, int* __restrict__ bcur16,
          unsigned int* __restrict__ ebuf) {
    __shared__ int lh[B_BKT], lbase[B_BKT], lc[B_BKT];
    int t = threadIdx.x;
    if (t < B_BKT) { lh[t] = 0; lc[t] = 0; }
    __syncthreads();
    int base = blockIdx.x * EDGES_PER_BLK;
    int sv[8], dv[8];
#pragma unroll
    for (int k = 0; k < 8; k++) {
        int e = base + k * 1024 + t;
        if (e < N_EDGES) {
            sv[k] = ei[e];
            dv[k] = ei[N_EDGES + e];
            atomicAdd(&lh[dv[k] >> BKT_SHIFT], 1);
        } else dv[k] = -1;
    }
    __syncthreads();
    if (t < B_BKT) lbase[t] = lh[t] ? atomicAdd(&bcur16[t * PAD], lh[t]) : 0;
    __syncthreads();
#pragma unroll
    for (int k = 0; k < 8; k++) {
        if (dv[k] >= 0) {
            int b = dv[k] >> BKT_SHIFT;
            int loc = atomicAdd(&lc[b], 1);
            ebuf[(size_t)b * CAPB + lbase[b] + loc] =
                ((unsigned)(dv[k] & 1023) << 18) | (unsigned)sv[k];
        }
    }
}

// S2: one block (1024 thr) per bucket. Degree histogram -> wave-shuffle
// exclusive scan (2 barriers, not 20) -> rowbeg/cnt/norm/xp -> placement.
__global__ void __launch_bounds__(1024)
k_bucket(const unsigned int* __restrict__ ebuf, const int* __restrict__ bcur16,
         const float* __restrict__ x, int* __restrict__ rowbeg,
         int* __restrict__ cntg, float* __restrict__ norm,
         float* __restrict__ xp, int* __restrict__ csrc) {
    __shared__ int hist[1024], rbase[1024];
    __shared__ int wsum[16];
    int b = blockIdx.x;
    int t = threadIdx.x;
    int lane = t & 63, wv = t >> 6;
    int count = bcur16[b * PAD];
    size_t ebase = (size_t)b * CAPB;
    int nbase = b << BKT_SHIFT;
    hist[t] = 0;
    __syncthreads();
    for (int i = t; i < count; i += 1024)
        atomicAdd(&hist[ebuf[ebase + i] >> 18], 1);
    __syncthreads();
    int v = hist[t];
    // wave-level inclusive scan
    int val = v;
#pragma unroll
    for (int off = 1; off < 64; off <<= 1) {
        int nn = __shfl_up(val, off);
        if (lane >= off) val += nn;
    }
    if (lane == 63) wsum[wv] = val;
    __syncthreads();
    if (t < 16) {
        int wval = wsum[t];
        int wincl = wval;
#pragma unroll
        for (int off = 1; off < 16; off <<= 1) {
            int nn = __shfl_up(wincl, off, 16);
            if (t >= off) wincl += nn;
        }
        wsum[t] = wincl - wval;   // exclusive wave offset
    }
    __syncthreads();
    int excl = (val - v) + wsum[wv];
    int rb = b * CAPB + excl;
    rbase[t] = rb;
    int n = nbase + t;
    if (n < N_NODES) {
        rowbeg[n] = rb;
        cntg[n] = v;
        float nm = rsqrtf((float)v + 1.0f);
        norm[n] = nm;
        xp[n] = x[n] * nm;
    }
    __syncthreads();
    hist[t] = 0;   // reuse as placement cursors
    __syncthreads();
    for (int i = t; i < count; i += 1024) {
        unsigned int w = ebuf[ebase + i];
        int ld = w >> 18;
        int loc = atomicAdd(&hist[ld], 1);
        csrc[rbase[ld] + loc] = (int)(w & 0x3FFFFu);
    }
}

// K5: layer-1 scalar gather s[n] = norm[n]*(xp[n] + sum xp[src]), fused
// block-level sum/sumsq (2 padded atomics per block: benign).
__global__ void __launch_bounds__(256)
k_gather1(const int* __restrict__ rowbeg, const int* __restrict__ cntg,
          const int* __restrict__ csrc, const float* __restrict__ xp,
          const float* __restrict__ norm, float* __restrict__ s,
          float* __restrict__ stats) {
    __shared__ float ls[256], lq[256];
    int n = blockIdx.x * blockDim.x + threadIdx.x;
    float val = 0.f;
    if (n < N_NODES) {
        int beg = rowbeg[n], dg = cntg[n];
        float acc = xp[n];
        for (int i = 0; i < dg; i++) acc += xp[csrc[beg + i]];
        val = norm[n] * acc;
        s[n] = val;
    }
    ls[threadIdx.x] = val; lq[threadIdx.x] = val * val;
    __syncthreads();
    for (int off = 128; off; off >>= 1) {
        if (threadIdx.x < (unsigned)off) {
            ls[threadIdx.x] += ls[threadIdx.x + off];
            lq[threadIdx.x] += lq[threadIdx.x + off];
        }
        __syncthreads();
    }
    if (threadIdx.x == 0) {
        atomAddF(&stats[S1SUM], ls[0]);
        atomAddF(&stats[S1SQ], lq[0]);
    }
}

// K7: fused layer-1 BN+ReLU (rank-1 form) + y1@W2, pre-scaled by norm[n].
// Writes A32 fp32 (layer-2 messages full precision for accuracy).
__global__ void __launch_bounds__(256)
k_fusedA(const float* __restrict__ s, const float* __restrict__ norm,
         const float* __restrict__ stats, const float* __restrict__ W1,
         const float* __restrict__ g1, const float* __restrict__ be1,
         const float* __restrict__ W2, float* __restrict__ A32) {
    __shared__ float w2[32 * 32];
    __shared__ float aj[32], sj[32];
    __shared__ float y[8][33];
    int tid = threadIdx.x;
    for (int i = tid; i < 1024; i += 256) w2[i] = W2[i];
    if (tid < 32) {
        float m   = stats[S1SUM] * (1.0f / N_NODES);
        float var = stats[S1SQ] * (1.0f / N_NODES) - m * m;
        float w = W1[tid];
        float a = g1[tid] * w * rsqrtf(var * w * w + BN_EPS);
        aj[tid] = a;
        sj[tid] = be1[tid] - m * a;
    }
    int nl = tid >> 5, j = tid & 31;
    int n = blockIdx.x * 8 + nl;
    __syncthreads();
    float sv = (n < N_NODES) ? s[n] : 0.f;
    y[nl][j] = fmaxf(aj[j] * sv + sj[j], 0.f);
    __syncthreads();
    if (n < N_NODES) {
        float acc = 0.f;
#pragma unroll
        for (int k = 0; k < 32; k++) acc += y[nl][k] * w2[k * 32 + j];
        A32[n * 32 + j] = acc * norm[n];
    }
}

// K8a: CSR gather-aggregate, fp32 messages, grid-stride (NBF blocks x ITF
// iters), fused per-channel stats: register accumulation across iters,
// wave shfl_xor reduce, then 64 PADDED atomics per block (<=1250/line).
__global__ void __launch_bounds__(256)
k_gatherF(const int* __restrict__ rowbeg, const int* __restrict__ cntg,
          const int* __restrict__ csrc, const float* __restrict__ A,
          const float* __restrict__ norm, float* __restrict__ B,
          float* __restrict__ sum, float* __restrict__ sumsq) {
    int tid = threadIdx.x;
    int nl = tid >> 3;            // 0..31 node lane
    int c = (tid & 7) * 4;        // channel group base
    float s0 = 0, s1 = 0, s2 = 0, s3 = 0, q0 = 0, q1 = 0, q2 = 0, q3 = 0;
#pragma unroll
    for (int it = 0; it < ITF; it++) {
        int n = (it * NBF + blockIdx.x) * 32 + nl;
        int beg = rowbeg[n], dg = cntg[n];
        float4 acc = *(const float4*)(A + n * 32 + c);    // self-loop
        int i = 0;
        for (; i + 1 < dg; i += 2) {
            int e0 = csrc[beg + i], e1 = csrc[beg + i + 1];
            float4 v0 = *(const float4*)(A + e0 * 32 + c);
            float4 v1 = *(const float4*)(A + e1 * 32 + c);
            acc.x += v0.x + v1.x; acc.y += v0.y + v1.y;
            acc.z += v0.z + v1.z; acc.w += v0.w + v1.w;
        }
        if (i < dg) {
            float4 v = *(const float4*)(A + csrc[beg + i] * 32 + c);
            acc.x += v.x; acc.y += v.y; acc.z += v.z; acc.w += v.w;
        }
        float nm = norm[n];
        float4 o = make_float4(acc.x * nm, acc.y * nm, acc.z * nm, acc.w * nm);
        *(float4*)(B + n * 32 + c) = o;
        s0 += o.x; s1 += o.y; s2 += o.z; s3 += o.w;
        q0 += o.x * o.x; q1 += o.y * o.y; q2 += o.z * o.z; q3 += o.w * o.w;
    }
    // reduce across the 8 node-lanes within each wave (lane bits 3..5)
#pragma unroll
    for (int mask = 32; mask >= 8; mask >>= 1) {
        s0 += __shfl_xor(s0, mask); s1 += __shfl_xor(s1, mask);
        s2 += __shfl_xor(s2, mask); s3 += __shfl_xor(s3, mask);
        q0 += __shfl_xor(q0, mask); q1 += __shfl_xor(q1, mask);
        q2 += __shfl_xor(q2, mask); q3 += __shfl_xor(q3, mask);
    }
    __shared__ float red[4][8][8];   // [wave][cg][8 stats]
    int wv = tid >> 6, ln = tid & 63;
    if (ln < 8) {
        float* r = red[wv][ln];
        r[0] = s0; r[1] = s1; r[2] = s2; r[3] = s3;
        r[4] = q0; r[5] = q1; r[6] = q2; r[7] = q3;
    }
    __syncthreads();
    if (tid < 8) {
        float tacc[8] = {0, 0, 0, 0, 0, 0, 0, 0};
#pragma unroll
        for (int w = 0; w < 4; w++)
#pragma unroll
            for (int k = 0; k < 8; k++) tacc[k] += red[w][tid][k];
        int cb = tid * 4;
#pragma unroll
        for (int k = 0; k < 4; k++) {
            atomAddF(&sum[(cb + k) * SSTR], tacc[k]);
            atomAddF(&sumsq[(cb + k) * SSTR], tacc[4 + k]);
        }
    }
}

// K10: fused BN+ReLU + y@W, pre-scaled by norm[n]. Reads B fp32, writes A16.
__global__ void __launch_bounds__(256)
k_fusedB(const float* __restrict__ norm, const float* __restrict__ sum,
         const float* __restrict__ sumsq, const float* __restrict__ g,
         const float* __restrict__ be, const float* __restrict__ W,
         const float* __restrict__ aggIn, __half* __restrict__ hOut) {
    __shared__ float wl[1024];
    __shared__ float sc[32], sh[32];
    __shared__ float y[8][33];
    int tid = threadIdx.x;
    for (int i = tid; i < 1024; i += 256) wl[i] = W[i];
    if (tid < 32) {
        float m   = sum[tid * SSTR] * (1.0f / N_NODES);
        float var = sumsq[tid * SSTR] * (1.0f / N_NODES) - m * m;
        float scj = g[tid] * rsqrtf(var + BN_EPS);
        sc[tid] = scj;
        sh[tid] = be[tid] - m * scj;
    }
    int nl = tid >> 5, j = tid & 31;
    int n = blockIdx.x * 8 + nl;
    __syncthreads();
    float yv = 0.f;
    if (n < N_NODES) yv = fmaxf(sc[j] * aggIn[n * 32 + j] + sh[j], 0.f);
    y[nl][j] = yv;
    __syncthreads();
    if (n < N_NODES) {
        float acc = 0.f;
#pragma unroll
        for (int k = 0; k < 32; k++) acc += y[nl][k] * wl[k * 32 + j];
        hOut[n * 32 + j] = __float2half(acc * norm[n]);
    }
}

__device__ __forceinline__ void load8h(const __half* p, float2& f0, float2& f1,
                                       float2& f2, float2& f3) {
    float4 raw = *(const float4*)p;              // one 16B load
    const __half2* h = (const __half2*)&raw;
    f0 = __half22float2(h[0]);
    f1 = __half22float2(h[1]);
    f2 = __half22float2(h[2]);
    f3 = __half22float2(h[3]);
}

// K8b: CSR gather-aggregate, f16 messages, grid-stride (NBH x ITH), fused
// per-channel stats with padded atomics (<=625/line).
__global__ void __launch_bounds__(256)
k_gatherH(const int* __restrict__ rowbeg, const int* __restrict__ cntg,
          const int* __restrict__ csrc, const __half* __restrict__ A,
          const float* __restrict__ norm, float* __restrict__ B,
          float* __restrict__ sum, float* __restrict__ sumsq) {
    int tid = threadIdx.x;
    int nl = tid >> 2;            // 0..63 node lane
    int c8 = (tid & 3) * 8;       // 8 channels per thread
    float st[16];
#pragma unroll
    for (int k = 0; k < 16; k++) st[k] = 0.f;
#pragma unroll
    for (int it = 0; it < ITH; it++) {
        int n = (it * NBH + blockIdx.x) * 64 + nl;
        int beg = rowbeg[n], dg = cntg[n];
        float2 a0, a1, a2, a3;
        load8h(A + n * 32 + c8, a0, a1, a2, a3);   // self-loop
        int i = 0;
        for (; i + 1 < dg; i += 2) {
            int e0 = csrc[beg + i], e1 = csrc[beg + i + 1];
            float2 b0, b1, b2, b3, c0, c1, c2, c3;
            load8h(A + e0 * 32 + c8, b0, b1, b2, b3);
            load8h(A + e1 * 32 + c8, c0, c1, c2, c3);
            a0.x += b0.x + c0.x; a0.y += b0.y + c0.y;
            a1.x += b1.x + c1.x; a1.y += b1.y + c1.y;
            a2.x += b2.x + c2.x; a2.y += b2.y + c2.y;
            a3.x += b3.x + c3.x; a3.y += b3.y + c3.y;
        }
        if (i < dg) {
            float2 b0, b1, b2, b3;
            load8h(A + csrc[beg + i] * 32 + c8, b0, b1, b2, b3);
            a0.x += b0.x; a0.y += b0.y; a1.x += b1.x; a1.y += b1.y;
            a2.x += b2.x; a2.y += b2.y; a3.x += b3.x; a3.y += b3.y;
        }
        float nm = norm[n];
        float o[8] = {a0.x * nm, a0.y * nm, a1.x * nm, a1.y * nm,
                      a2.x * nm, a2.y * nm, a3.x * nm, a3.y * nm};
        *(float4*)(B + n * 32 + c8)     = make_float4(o[0], o[1], o[2], o[3]);
        *(float4*)(B + n * 32 + c8 + 4) = make_float4(o[4], o[5], o[6], o[7]);
#pragma unroll
        for (int k = 0; k < 8; k++) { st[k] += o[k]; st[8 + k] += o[k] * o[k]; }
    }
    // reduce across the 16 node-lanes within each wave (lane bits 2..5)
#pragma unroll
    for (int mask = 32; mask >= 4; mask >>= 1)
#pragma unroll
        for (int k = 0; k < 16; k++) st[k] += __shfl_xor(st[k], mask);
    __shared__ float red[4][4][16];   // [wave][cg][16 stats]
    int wv = tid >> 6, ln = tid & 63;
    if (ln < 4) {
#pragma unroll
        for (int k = 0; k < 16; k++) red[wv][ln][k] = st[k];
    }
    __syncthreads();
    if (tid < 4) {
        float tacc[16];
#pragma unroll
        for (int k = 0; k < 16; k++) tacc[k] = 0.f;
#pragma unroll
        for (int w = 0; w < 4; w++)
#pragma unroll
            for (int k = 0; k < 16; k++) tacc[k] += red[w][tid][k];
        int cb = tid * 8;
#pragma unroll
        for (int k = 0; k < 8; k++) {
            atomAddF(&sum[(cb + k) * SSTR], tacc[k]);
            atomAddF(&sumsq[(cb + k) * SSTR], tacc[8 + k]);
        }
    }
}

// K11: final BN+ReLU + dot with fcW + fcb. Reads padded stats.
__global__ void __launch_bounds__(256)
k_final(const float* __restrict__ aggIn, const float* __restrict__ sum,
        const float* __restrict__ sumsq, const float* __restrict__ g,
        const float* __restrict__ be, const float* __restrict__ fcW,
        const float* __restrict__ fcb, float* __restrict__ out) {
    __shared__ float sc[32], sh[32], fw[32];
    int tid = threadIdx.x;
    if (tid < 32) {
        float m   = sum[tid * SSTR] * (1.0f / N_NODES);
        float var = sumsq[tid * SSTR] * (1.0f / N_NODES) - m * m;
        float scj = g[tid] * rsqrtf(var + BN_EPS);
        sc[tid] = scj;
        sh[tid] = be[tid] - m * scj;
        fw[tid] = fcW[tid];
    }
    __syncthreads();
    int nl = tid >> 5, j = tid & 31;
    int n = blockIdx.x * 8 + nl;
    float v = 0.f;
    if (n < N_NODES) v = fmaxf(sc[j] * aggIn[n * 32 + j] + sh[j], 0.f) * fw[j];
    for (int off = 16; off; off >>= 1) v += __shfl_down(v, off, 32);
    if (j == 0 && n < N_NODES) out[n] = v + fcb[0];
}

extern "C" void kernel_launch(void* const* d_in, const int* in_sizes, int n_in,
                              void* d_out, int out_size, void* d_ws, size_t ws_size,
                              hipStream_t stream) {
    const float* x   = (const float*)d_in[0];
    const int*   ei  = (const int*)d_in[1];
    // d_in[2] edge_attr: unused by the reference
    const float* W1  = (const float*)d_in[3];
    // b1/b2/b3 cancel under training-mode BN
    const float* g1  = (const float*)d_in[5];
    const float* be1 = (const float*)d_in[6];
    const float* W2  = (const float*)d_in[7];
    const float* g2  = (const float*)d_in[9];
    const float* be2 = (const float*)d_in[10];
    const float* W3  = (const float*)d_in[11];
    const float* g3  = (const float*)d_in[13];
    const float* be3 = (const float*)d_in[14];
    const float* fcW = (const float*)d_in[15];
    const float* fcb = (const float*)d_in[16];
    float* out = (float*)d_out;

    // Workspace. Region0 [0, 25.6M) time-multiplexed (strictly ordered):
    //   ebuf u32[196*14336] = 11.2MB (last read k_bucket)
    //   A32 fp32 N*32 = 25.6MB (k_fusedA -> k_gatherF)
    //   A16 f16  N*32 = 12.8MB (k_fusedB -> k_gatherH)
    char* base = (char*)d_ws;
    float*        A32  = (float*)base;
    __half*       A16  = (__half*)base;
    unsigned int* ebuf = (unsigned int*)base;
    float*  B      = (float*)(base + (size_t)N_NODES * 32 * 4);   // 25.6MB
    int*    csrc   = (int*)(base + (size_t)N_NODES * 32 * 8);     // 11.2MB
    int*    rowbeg = csrc + (size_t)B_BKT * CAPB;
    int*    cntg   = rowbeg + N_NODES;
    float*  norm   = (float*)(cntg + N_NODES);
    float*  xp     = norm + N_NODES;
    float*  s      = xp + N_NODES;
    float*  stats  = s + N_NODES;                  // [4096]
    int*    bcur16 = (int*)(stats + 4096);         // [B_BKT*16]

    const int nbN = (N_NODES + 255) / 256;
    const int nbZ = (4096 + 255) / 256;            // covers B_BKT*PAD=3136 too
    const int nbNode8 = (N_NODES + 7) / 8;

    k_init   <<<nbZ, 256, 0, stream>>>(bcur16, stats);
    k_scatter<<<NB_SCAT, 1024, 0, stream>>>(ei, bcur16, ebuf);
    k_bucket <<<B_BKT, 1024, 0, stream>>>(ebuf, bcur16, x, rowbeg, cntg, norm, xp, csrc);
    k_gather1<<<nbN, 256, 0, stream>>>(rowbeg, cntg, csrc, xp, norm, s, stats);
    k_fusedA <<<nbNode8, 256, 0, stream>>>(s, norm, stats, W1, g1, be1, W2, A32);
    k_gatherF<<<NBF, 256, 0, stream>>>(rowbeg, cntg, csrc, A32, norm, B,
                                       stats + L2SUM, stats + L2SQ);
    k_fusedB <<<nbNode8, 256, 0, stream>>>(norm, stats + L2SUM, stats + L2SQ,
                                           g2, be2, W3, B, A16);
    k_gatherH<<<NBH, 256, 0, stream>>>(rowbeg, cntg, csrc, A16, norm, B,
                                       stats + L3SUM, stats + L3SQ);
    k_final  <<<nbNode8, 256, 0, stream>>>(B, stats + L3SUM, stats + L3SQ,
                                           g3, be3, fcW, fcb, out);
}